// Round 7
// baseline (583.917 us; speedup 1.0000x reference)
//
#include <hip/hip_runtime.h>
#include <stdint.h>

// ---------------------------------------------------------------------------
// GRU-D (MIMIC) forward. B=512, T=256, D=128, H=128, S=32.
// Phase 0 : pack weights Wcat_t[n][k] bf16 + bias[512]
// Phase 0b: build_A: A[m=t*B+b][384] = [x_hat | mask | delta] bf16.
//           ROUND 7: one block per b, loop over all T -> input reads are
//           FULLY CONTIGUOUS (4 streams x 128KB per block; r0-r6 read 512B
//           islands at 128KB stride). wdgx/bdgx/xmean hoisted to registers
//           (fixed d-quad per thread). Abuf written m-major (coalesced 256B
//           segments) with NON-TEMPORAL stores (single-use 101MB buffer).
// Phase 1 : gemm_phase1 (r4 verbatim, best measured): 128x256 tile, 2 passes
//           over N, 3-buffer global_load_lds pipeline, vmcnt(6), 2 blocks/CU.
//           E ALWAYS bf16 (r5 lesson). E[t][blk=b>>4][n(512)][b&15].
// Phase 2 : sequential scan (r0 verbatim, best measured 212us local optimum).
// LESSONS: r1 fewer waves = regression (no latency hiding). r2 conflict-free
//   LDS = null (conflicts not critical path). r3 2 groups/block = regression
//   (CU count halved). r4 128x256 gemm tile: -31us. r5 f32-E ws-threshold
//   bug: +108us. r6 fused build_A+gemm = null vs r4 (1 blk/CU, convert on
//   critical path, island reads). Producer wins come from access-pattern /
//   redundancy fixes, not fusion. Prior session: producer/consumer fusion
//   with device atomics regressed 3.3x; keep separate dispatches.
// ---------------------------------------------------------------------------

#define B_ 512
#define T_ 256
#define D_ 128
#define H_ 128
#define S_ 32
#define NE 512   // E width: z(128) r(128) h(128) gamma(128)
#define KA 384   // A width: xhat(128) mask(128) delta(128)
#define M_ (B_*T_)
#define HP 136   // padded LDS row stride (shorts / floats)
#define ESLAB ((size_t)NE * 16)        // elements per (t,blk) slab = 8192
#define ESTRIDE ((size_t)32 * ESLAB)   // elements per t = 262144

typedef __attribute__((ext_vector_type(8))) short short8;
typedef __attribute__((ext_vector_type(4))) float f32x4;

// raw barrier: LDS visibility only (lgkm drain), no vmcnt(0) drain of
// in-flight global prefetches (which __syncthreads would force).
#define BAR_LDS() asm volatile("s_waitcnt lgkmcnt(0)\n\ts_barrier" ::: "memory")

__device__ __forceinline__ unsigned short f2bf(float f) {
  union { float f; uint32_t u; } v; v.f = f;
  return (unsigned short)((v.u + 0x7FFFu + ((v.u >> 16) & 1u)) >> 16);
}
// cheap round-half-up bf16 (2 VALU ops) — scan LDS stores only
__device__ __forceinline__ unsigned short f2bf_fast(float f) {
  union { float f; uint32_t u; } v; v.f = f;
  return (unsigned short)((v.u + 0x8000u) >> 16);
}
__device__ __forceinline__ float bf2f(uint32_t s) {
  union { uint32_t u; float f; } v; v.u = s << 16;
  return v.f;
}

__device__ __forceinline__ uint2 ldraw(const unsigned short* p) { return *(const uint2*)p; }
__device__ __forceinline__ void unp(uint2 v, float o[4]) {
  o[0] = bf2f(v.x & 0xffffu); o[1] = bf2f(v.x >> 16);
  o[2] = bf2f(v.y & 0xffffu); o[3] = bf2f(v.y >> 16);
}
__device__ __forceinline__ void st4(unsigned short* p, const float v[4]) {
  uint2 u;
  u.x = (uint32_t)f2bf(v[0]) | ((uint32_t)f2bf(v[1]) << 16);
  u.y = (uint32_t)f2bf(v[2]) | ((uint32_t)f2bf(v[3]) << 16);
  *(uint2*)p = u;
}

__device__ __forceinline__ float fsigmoid(float x) {
  return __builtin_amdgcn_rcpf(1.f + __expf(-x));
}
__device__ __forceinline__ float ftanh(float x) {
  return 1.f - 2.f * __builtin_amdgcn_rcpf(1.f + __expf(2.f * x));
}

#define ASYNC_CP16(gsrc, ldst) \
  __builtin_amdgcn_global_load_lds((const __attribute__((address_space(1))) void*)(gsrc), \
                                   (__attribute__((address_space(3))) void*)(ldst), 16, 0, 0)

// --------------------------------------------------------------------------
__global__ void prep_weights(const float* __restrict__ Wz, const float* __restrict__ Vz,
                             const float* __restrict__ Wr, const float* __restrict__ Vr,
                             const float* __restrict__ Wh, const float* __restrict__ Vh,
                             const float* __restrict__ Wdgh,
                             const float* __restrict__ bz, const float* __restrict__ br,
                             const float* __restrict__ bh, const float* __restrict__ bdgh,
                             unsigned short* __restrict__ Wcat, float* __restrict__ bias)
{
  int id = blockIdx.x * 256 + threadIdx.x;
  if (id < NE * KA) {
    int n = id / KA, k = id - n * KA;
    float v = 0.f;
    if (n < 384) {
      int nn = n & 127;
      const float* W = (n < 128) ? Wz : (n < 256) ? Wr : Wh;
      const float* V = (n < 128) ? Vz : (n < 256) ? Vr : Vh;
      if (k < 128)      v = W[nn * 128 + k];
      else if (k < 256) v = V[nn * 128 + (k - 128)];
    } else {
      if (k >= 256) v = Wdgh[(n - 384) * 128 + (k - 256)];
    }
    Wcat[id] = f2bf(v);
  }
  if (id < NE) {
    bias[id] = (id < 128) ? bz[id] : (id < 256) ? br[id - 128]
             : (id < 384) ? bh[id - 256] : bdgh[id - 384];
  }
}

// --------------------------------------------------------------------------
// ROUND 7 build_A: one block per batch row b; 256 threads sweep T in chunks
// of 8 t-rows (thread -> fixed d-quad dq=(tid&31)*4, t-offset tof=tid>>5).
// Reads are fully contiguous per stream (4KB/iter/stream, 128KB/block/stream).
// Per-thread constants wdgx/bdgx/xmean hoisted. Writes m-major Abuf rows
// (m = t*512 + b): 3 x 8B per thread, 32-lane segments = 256B coalesced,
// via non-temporal stores (Abuf is single-use, don't pollute L2).
__global__ __launch_bounds__(256, 4) void build_A(
    const float* __restrict__ x, const float* __restrict__ mask,
    const float* __restrict__ delta, const float* __restrict__ xlast,
    const float* __restrict__ xmean,
    const float* __restrict__ wdgx, const float* __restrict__ bdgx,
    unsigned short* __restrict__ Abuf)
{
  const int b = blockIdx.x;
  const int dq = (threadIdx.x & 31) * 4;   // d-quad this thread owns
  const int tof = threadIdx.x >> 5;        // 0..7
  const float4 wv = *(const float4*)(wdgx + dq);
  const float4 cv = *(const float4*)(bdgx + dq);
  const float4 uv = *(const float4*)(xmean + (size_t)b * D_ + dq);
  const float* wp = (const float*)&wv;
  const float* cp = (const float*)&cv;
  const float* up = (const float*)&uv;
  const size_t base = (size_t)b * T_ * D_;

  for (int it = 0; it < T_ / 8; ++it) {
    const int t = it * 8 + tof;
    const size_t src = base + (size_t)t * D_ + dq;
    float4 xv = *(const float4*)(x + src);
    float4 mv = *(const float4*)(mask + src);
    float4 dv = *(const float4*)(delta + src);
    float4 lv = *(const float4*)(xlast + src);
    const float* xp = (const float*)&xv; const float* mp = (const float*)&mv;
    const float* dp = (const float*)&dv; const float* lp = (const float*)&lv;
    unsigned short xh[4], mm[4], dd[4];
    #pragma unroll
    for (int i = 0; i < 4; ++i) {
      float g = __expf(-fmaxf(wp[i] * dp[i] + cp[i], 0.f));
      float xhat = mp[i] * xp[i] + (1.f - mp[i]) * (g * lp[i] + (1.f - g) * up[i]);
      xh[i] = f2bf(xhat); mm[i] = f2bf(mp[i]); dd[i] = f2bf(dp[i]);
    }
    unsigned long long px = (unsigned long long)xh[0] | ((unsigned long long)xh[1] << 16)
                          | ((unsigned long long)xh[2] << 32) | ((unsigned long long)xh[3] << 48);
    unsigned long long pm = (unsigned long long)mm[0] | ((unsigned long long)mm[1] << 16)
                          | ((unsigned long long)mm[2] << 32) | ((unsigned long long)mm[3] << 48);
    unsigned long long pd = (unsigned long long)dd[0] | ((unsigned long long)dd[1] << 16)
                          | ((unsigned long long)dd[2] << 32) | ((unsigned long long)dd[3] << 48);
    unsigned short* rowp = Abuf + (size_t)(t * B_ + b) * KA;
    __builtin_nontemporal_store(px, (unsigned long long*)(rowp + dq));
    __builtin_nontemporal_store(pm, (unsigned long long*)(rowp + 128 + dq));
    __builtin_nontemporal_store(pd, (unsigned long long*)(rowp + 256 + dq));
  }
}

// --------------------------------------------------------------------------
// 128x256 tile, K=384 in 12 iters of 32 (r4 verbatim). 3-buffer async
// pipeline: iter kt: wait vmcnt(6) [stage kt done, kt+1 in flight],
// s_barrier, issue stage(kt+2), MFMA on buf kt%3. 6 loads/thread/stage.
// Per wave: 64x128 output = acc[4][8]; 2 blocks/CU (72KB LDS).
__global__ __launch_bounds__(256, 2) void gemm_phase1(
    const unsigned short* __restrict__ Abuf, const unsigned short* __restrict__ Wcat,
    const float* __restrict__ bias, unsigned short* __restrict__ E)
{
  __shared__ unsigned short As[3][4096];   // 128x32 bf16
  __shared__ unsigned short Bs[3][8192];   // 256x32 bf16
  const int tid = threadIdx.x;
  const int wave = tid >> 6, lane = tid & 63;
  const int q = lane >> 4, rl = lane & 15;
  const int m0 = blockIdx.x * 128;
  const int n0 = blockIdx.y * 256;
  const int wm = (wave >> 1) * 64, wn = (wave & 1) * 128;

  f32x4 acc[4][8];
  #pragma unroll
  for (int a = 0; a < 4; ++a)
    #pragma unroll
    for (int b = 0; b < 8; ++b) acc[a][b] = (f32x4){0.f, 0.f, 0.f, 0.f};

  // stage(kt): copy A 128x32 + B 256x32 bf16 tiles for k-slice kt into buf kt%3
  #define STAGE(kt_) do {                                                     \
    const int kbase_ = (kt_) * 32; const int buf_ = (kt_) % 3;                \
    _Pragma("unroll")                                                         \
    for (int i = 0; i < 2; ++i) {                                             \
      int chunk = i * 256 + wave * 64 + lane;                                 \
      int row = chunk >> 2, kc = chunk & 3;                                   \
      ASYNC_CP16(Abuf + (size_t)(m0 + row) * KA + kbase_ + kc * 8,            \
                 &As[buf_][(i * 256 + wave * 64) * 8]);                       \
    }                                                                         \
    _Pragma("unroll")                                                         \
    for (int i = 0; i < 4; ++i) {                                             \
      int chunk = i * 256 + wave * 64 + lane;                                 \
      int row = chunk >> 2, kc = chunk & 3;                                   \
      ASYNC_CP16(Wcat + (size_t)(n0 + row) * KA + kbase_ + kc * 8,            \
                 &Bs[buf_][(i * 256 + wave * 64) * 8]);                       \
    }                                                                         \
  } while (0)

  STAGE(0);
  STAGE(1);

  #pragma unroll
  for (int kt = 0; kt < 12; ++kt) {
    if (kt == 11) asm volatile("s_waitcnt vmcnt(0)" ::: "memory");
    else          asm volatile("s_waitcnt vmcnt(6)" ::: "memory");
    asm volatile("s_barrier" ::: "memory");
    if (kt < 10) STAGE(kt + 2);
    const int buf = kt % 3;
    short8 af[4], bfr[8];
    #pragma unroll
    for (int tm = 0; tm < 4; ++tm)
      af[tm] = *(const short8*)(&As[buf][(wm + tm * 16 + rl) * 32 + q * 8]);
    #pragma unroll
    for (int tn = 0; tn < 8; ++tn)
      bfr[tn] = *(const short8*)(&Bs[buf][(wn + tn * 16 + rl) * 32 + q * 8]);
    #pragma unroll
    for (int tm = 0; tm < 4; ++tm)
      #pragma unroll
      for (int tn = 0; tn < 8; ++tn)
        acc[tm][tn] = __builtin_amdgcn_mfma_f32_16x16x32_bf16(af[tm], bfr[tn], acc[tm][tn], 0, 0, 0);
  }
  #undef STAGE

  // epilogue: write E in block-local scan layout E[t][b>>4][n][b&15]
  const int t = m0 >> 9;             // constant per block
  const int bbase = m0 & (B_ - 1);
  #pragma unroll
  for (int tn = 0; tn < 8; ++tn) {
    int n = n0 + wn + tn * 16 + rl;
    float bv = bias[n];
    bool isg = (n >= 384);
    #pragma unroll
    for (int tm = 0; tm < 4; ++tm) {
      int brow = bbase + wm + tm * 16;     // multiple of 16
      float v[4];
      #pragma unroll
      for (int reg = 0; reg < 4; ++reg) {
        float xv = acc[tm][tn][reg] + bv;
        v[reg] = isg ? __expf(-fmaxf(xv, 0.f)) : xv;
      }
      st4(E + ((size_t)t * 32 + (brow >> 4)) * ESLAB + (size_t)n * 16 + q * 4, v);
    }
  }
}

// --------------------------------------------------------------------------
// Scan (round-0 version, best measured 212us): 32 blocks x 16 batch rows,
// 8 waves x 16 H-cols; vectorized E loads prefetched one step ahead; raw
// lgkm-only barriers; rcp-based sigmoid/tanh; classifier fused.
__global__ __launch_bounds__(512, 2) void grud_scan(
    const unsigned short* __restrict__ E,
    const float* __restrict__ Uz, const float* __restrict__ Ur, const float* __restrict__ Uh,
    const float* __restrict__ hs0, const float* __restrict__ statics,
    const float* __restrict__ Wout, const float* __restrict__ bout,
    float* __restrict__ out)
{
  __shared__ unsigned short hdec[16 * HP];
  __shared__ unsigned short rhb[16 * HP];
  __shared__ float hfin[16 * HP];
  const int tid = threadIdx.x;
  const int wave = tid >> 6, lane = tid & 63;
  const int q = lane >> 4, rl = lane & 15;
  const int col = wave * 16 + rl;       // H column this lane owns (C/D + B-frag)
  const int b0 = blockIdx.x * 16;

  // U_* as resident B-fragments: B[k][n]=U[n][k]; lane: n=col, k=kc*32+q*8+j
  short8 uz[4], ur[4], uh[4];
  #pragma unroll
  for (int kc = 0; kc < 4; ++kc) {
    int koff = kc * 32 + q * 8;
    const float* pzw = Uz + col * H_ + koff;
    const float* prw = Ur + col * H_ + koff;
    const float* phw = Uh + col * H_ + koff;
    #pragma unroll
    for (int j = 0; j < 8; ++j) {
      uz[kc][j] = (short)f2bf(pzw[j]);
      ur[kc][j] = (short)f2bf(prw[j]);
      uh[kc][j] = (short)f2bf(phw[j]);
    }
  }

  // per-lane E pointers (block-local layout): slab = blk*ESLAB, +n*16 + q*4
  const unsigned short* pz = E + (size_t)blockIdx.x * ESLAB + (size_t)col * 16 + q * 4;
  const unsigned short* pr = pz + 128 * 16;
  const unsigned short* ph = pz + 256 * 16;
  const unsigned short* pg = pz + 384 * 16;

  uint2 cz, cr, chh, cg, nz{}, nr{}, nh{}, ng{};
  cz  = ldraw(pz);                 // slab t=0
  cr  = ldraw(pr);
  chh = ldraw(ph);
  cg  = ldraw(pg + ESTRIDE);       // gamma for step 0's epilogue = slab 1
  uint2 g0raw = ldraw(pg);         // gamma at t=0 for h-init

  // h state (fp32) in C/D layout: rows q*4+reg, col
  float hd[4], g0[4];
  unp(g0raw, g0);
  #pragma unroll
  for (int reg = 0; reg < 4; ++reg) {
    int row = q * 4 + reg;
    float h0 = hs0[(b0 + row) * H_ + col];
    hd[reg] = g0[reg] * h0;
    hdec[row * HP + col] = f2bf_fast(hd[reg]);
  }
  BAR_LDS();

  for (int t = 0; t < T_; ++t) {
    // ---- prefetch E for step t+1 (and gamma for t+2) ----
    if (t + 1 < T_) {
      size_t off = (size_t)(t + 1) * ESTRIDE;
      nz = ldraw(pz + off); nr = ldraw(pr + off); nh = ldraw(ph + off);
      if (t + 2 < T_) ng = ldraw(pg + (size_t)(t + 2) * ESTRIDE);
    }
    float Pz[4], Pr[4], Ph[4];
    unp(cz, Pz); unp(cr, Pr); unp(chh, Ph);

    // A-frags of decayed h from LDS
    short8 af[4];
    #pragma unroll
    for (int kc = 0; kc < 4; ++kc)
      af[kc] = *(const short8*)(&hdec[rl * HP + kc * 32 + q * 8]);
    f32x4 accz = (f32x4){0.f,0.f,0.f,0.f}, accr = (f32x4){0.f,0.f,0.f,0.f};
    #pragma unroll
    for (int kc = 0; kc < 4; ++kc) {
      accz = __builtin_amdgcn_mfma_f32_16x16x32_bf16(af[kc], uz[kc], accz, 0, 0, 0);
      accr = __builtin_amdgcn_mfma_f32_16x16x32_bf16(af[kc], ur[kc], accr, 0, 0, 0);
    }
    float zz[4];
    #pragma unroll
    for (int reg = 0; reg < 4; ++reg) {
      zz[reg] = fsigmoid(accz[reg] + Pz[reg]);
      float rr = fsigmoid(accr[reg] + Pr[reg]);
      rhb[(q * 4 + reg) * HP + col] = f2bf_fast(rr * hd[reg]);
    }
    BAR_LDS();                                         // barrier 1

    short8 ar[4];
    #pragma unroll
    for (int kc = 0; kc < 4; ++kc)
      ar[kc] = *(const short8*)(&rhb[rl * HP + kc * 32 + q * 8]);
    f32x4 acch = (f32x4){0.f,0.f,0.f,0.f};
    #pragma unroll
    for (int kc = 0; kc < 4; ++kc)
      acch = __builtin_amdgcn_mfma_f32_16x16x32_bf16(ar[kc], uh[kc], acch, 0, 0, 0);

    if (t < T_ - 1) {
      float Gn[4];
      unp(cg, Gn);
      #pragma unroll
      for (int reg = 0; reg < 4; ++reg) {
        float ht = ftanh(acch[reg] + Ph[reg]);
        float hn = hd[reg] + zz[reg] * (ht - hd[reg]);   // (1-z)h + z*h~
        hd[reg] = Gn[reg] * hn;                          // fold next-step decay
        hdec[(q * 4 + reg) * HP + col] = f2bf_fast(hd[reg]);
      }
    } else {
      #pragma unroll
      for (int reg = 0; reg < 4; ++reg) {
        float ht = ftanh(acch[reg] + Ph[reg]);
        float hn = hd[reg] + zz[reg] * (ht - hd[reg]);
        hfin[(q * 4 + reg) * HP + col] = hn;
      }
    }
    BAR_LDS();                                         // barrier 2

    cz = nz; cr = nr; chh = nh; cg = ng;
  }

  // fused classifier: 32 threads per batch row
  {
    int row = tid >> 5, j = tid & 31;
    float acc = 0.f;
    #pragma unroll
    for (int c0 = 0; c0 < 4; ++c0)
      acc += hfin[row * HP + j + c0 * 32] * Wout[j + c0 * 32];
    acc += statics[(size_t)(b0 + row) * S_ + j] * Wout[H_ + j];
    #pragma unroll
    for (int off = 16; off >= 1; off >>= 1)
      acc += __shfl_down(acc, off, 32);
    if (j == 0) out[b0 + row] = acc + bout[0];
  }
}

// --------------------------------------------------------------------------
static void launch_all(void* const* d_in, float* out, char* ws, hipStream_t stream)
{
  const float* x      = (const float*)d_in[0];
  const float* statics= (const float*)d_in[1];
  const float* mask   = (const float*)d_in[2];
  const float* delta  = (const float*)d_in[3];
  const float* xlast  = (const float*)d_in[4];
  const float* xmean  = (const float*)d_in[5];
  const float* hs0    = (const float*)d_in[6];
  const float* wdgx   = (const float*)d_in[7];
  const float* bdgx   = (const float*)d_in[8];
  const float* Wdgh   = (const float*)d_in[9];
  const float* bdgh   = (const float*)d_in[10];
  const float* Wz     = (const float*)d_in[11];
  const float* Uz     = (const float*)d_in[12];
  const float* Vz     = (const float*)d_in[13];
  const float* bz     = (const float*)d_in[14];
  const float* Wr     = (const float*)d_in[15];
  const float* Ur     = (const float*)d_in[16];
  const float* Vr     = (const float*)d_in[17];
  const float* br     = (const float*)d_in[18];
  const float* Wh     = (const float*)d_in[19];
  const float* Uh     = (const float*)d_in[20];
  const float* Vh     = (const float*)d_in[21];
  const float* bh     = (const float*)d_in[22];
  const float* Wout   = (const float*)d_in[23];
  const float* bout   = (const float*)d_in[24];

  const size_t eBytes = (size_t)M_ * NE * 2;          // bf16 E, always
  const size_t aBytes = (size_t)M_ * KA * 2;
  const size_t wBytes = (size_t)NE * KA * 2;
  unsigned short* E = (unsigned short*)ws;
  unsigned short* Abuf = (unsigned short*)(ws + eBytes);
  unsigned short* Wcat = (unsigned short*)(ws + eBytes + aBytes);
  float* bias = (float*)(ws + eBytes + aBytes + wBytes);

  prep_weights<<<768, 256, 0, stream>>>(Wz, Vz, Wr, Vr, Wh, Vh, Wdgh,
                                        bz, br, bh, bdgh, Wcat, bias);
  build_A<<<B_, 256, 0, stream>>>(x, mask, delta, xlast, xmean,
                                  wdgx, bdgx, Abuf);
  gemm_phase1<<<dim3(M_ / 128, NE / 256), 256, 0, stream>>>(Abuf, Wcat, bias, E);
  grud_scan<<<B_ / 16, 512, 0, stream>>>(E, Uz, Ur, Uh, hs0, statics, Wout, bout, out);
}

extern "C" void kernel_launch(void* const* d_in, const int* in_sizes, int n_in,
                              void* d_out, int out_size, void* d_ws, size_t ws_size,
                              hipStream_t stream)
{
  char* ws = (char*)d_ws;
  float* out = (float*)d_out;
  const size_t needBF = (size_t)M_ * NE * 2 + (size_t)M_ * KA * 2
                      + (size_t)NE * KA * 2 + 8192;    // ~236 MB, bf16 E always
  if (ws_size >= needBF) launch_all(d_in, out, ws, stream);
  // else: workspace too small — launch nothing (fails visibly)
}

// Round 10
// 546.395 us; speedup vs baseline: 1.0687x; 1.0687x over previous
//
#include <hip/hip_runtime.h>
#include <stdint.h>

// ---------------------------------------------------------------------------
// GRU-D (MIMIC) forward. B=512, T=256, D=128, H=128, S=32.
// Phase 0 : pack weights Wcat_t[n][k] bf16 + bias[512]
// Phase 1 : gemm_fused (r6 config -- best measured 567.9us total):
//           E = A @ Wcat^T with A built ON THE FLY. BM=128 (16b x 8t tile),
//           BN=512 (A consumed once), 512 thr, acc[4][8]. mask/delta bf16
//           stashed in VGPRs during kt0-3 -> kt4-11 zero A-loads. 2-buffer
//           LDS pipeline, vmcnt(0)-exact waits, one barrier/iter.
//           ROUND 10 (= r8 intent, twice compile-fixed): input streams
//           x/mask/delta/xlast via __builtin_nontemporal_load (268MB
//           single-use; keep Wcat + E write-allocate lines L2-resident).
//           r8: dead-branch OOB constant index -> -Warray-bounds error.
//           r9: __builtin_nontemporal_load rejects HIP float4 (struct);
//           needs NATIVE vector type -> load through f32x4 ext_vector.
//           E ALWAYS bf16 (r5 lesson). E[t][blk=b>>4][n(512)][b&15].
// Phase 2 : sequential scan (r0 verbatim, 212us local optimum -- pinned
//           across 8 rounds; VALU-throughput-bound at the structural
//           32-CU cap; r1/r2/r3 falsified all alternative structures).
// LESSONS: r1 fewer waves = regression. r2 conflict-free LDS = null.
//   r3 2 groups/block = regression (CU cap). r4 128x256 tile: -31us.
//   r5 f32-E ws-threshold bug: +108us. r6 fused producer: best (567.9).
//   r7 build_A NT-stores: regression (never NT-store cache-communicated
//   intermediates). r8/r9 compile errors: keep constant indices in-range
//   even in dead code; NT builtins need ext_vector types, not HIP structs.
// ---------------------------------------------------------------------------

#define B_ 512
#define T_ 256
#define D_ 128
#define H_ 128
#define S_ 32
#define NE 512   // E width: z(128) r(128) h(128) gamma(128)
#define KA 384   // A width: xhat(128) mask(128) delta(128)
#define M_ (B_*T_)
#define HP 136   // padded LDS row stride (shorts / floats)
#define ESLAB ((size_t)NE * 16)        // elements per (t,blk) slab = 8192
#define ESTRIDE ((size_t)32 * ESLAB)   // elements per t = 262144

typedef __attribute__((ext_vector_type(8))) short short8;
typedef __attribute__((ext_vector_type(4))) float f32x4;

// raw barrier: LDS visibility only (lgkm drain), no vmcnt(0) drain of
// in-flight global prefetches (which __syncthreads would force).
#define BAR_LDS() asm volatile("s_waitcnt lgkmcnt(0)\n\ts_barrier" ::: "memory")

__device__ __forceinline__ unsigned short f2bf(float f) {
  union { float f; uint32_t u; } v; v.f = f;
  return (unsigned short)((v.u + 0x7FFFu + ((v.u >> 16) & 1u)) >> 16);
}
// cheap round-half-up bf16 (2 VALU ops) — scan LDS stores only
__device__ __forceinline__ unsigned short f2bf_fast(float f) {
  union { float f; uint32_t u; } v; v.f = f;
  return (unsigned short)((v.u + 0x8000u) >> 16);
}
__device__ __forceinline__ float bf2f(uint32_t s) {
  union { uint32_t u; float f; } v; v.u = s << 16;
  return v.f;
}

__device__ __forceinline__ uint2 ldraw(const unsigned short* p) { return *(const uint2*)p; }
__device__ __forceinline__ void unp(uint2 v, float o[4]) {
  o[0] = bf2f(v.x & 0xffffu); o[1] = bf2f(v.x >> 16);
  o[2] = bf2f(v.y & 0xffffu); o[3] = bf2f(v.y >> 16);
}
__device__ __forceinline__ void st4(unsigned short* p, const float v[4]) {
  uint2 u;
  u.x = (uint32_t)f2bf(v[0]) | ((uint32_t)f2bf(v[1]) << 16);
  u.y = (uint32_t)f2bf(v[2]) | ((uint32_t)f2bf(v[3]) << 16);
  *(uint2*)p = u;
}

__device__ __forceinline__ float fsigmoid(float x) {
  return __builtin_amdgcn_rcpf(1.f + __expf(-x));
}
__device__ __forceinline__ float ftanh(float x) {
  return 1.f - 2.f * __builtin_amdgcn_rcpf(1.f + __expf(2.f * x));
}

// non-temporal 16B load (single-use streams; no L2 allocate).
// NOTE: __builtin_nontemporal_load requires a NATIVE vector type
// (ext_vector_type), not HIP's float4 struct (r9 compile error).
__device__ __forceinline__ f32x4 ldnt4(const float* p) {
  return __builtin_nontemporal_load((const f32x4*)p);
}

#define ASYNC_CP16(gsrc, ldst) \
  __builtin_amdgcn_global_load_lds((const __attribute__((address_space(1))) void*)(gsrc), \
                                   (__attribute__((address_space(3))) void*)(ldst), 16, 0, 0)

// --------------------------------------------------------------------------
__global__ void prep_weights(const float* __restrict__ Wz, const float* __restrict__ Vz,
                             const float* __restrict__ Wr, const float* __restrict__ Vr,
                             const float* __restrict__ Wh, const float* __restrict__ Vh,
                             const float* __restrict__ Wdgh,
                             const float* __restrict__ bz, const float* __restrict__ br,
                             const float* __restrict__ bh, const float* __restrict__ bdgh,
                             unsigned short* __restrict__ Wcat, float* __restrict__ bias)
{
  int id = blockIdx.x * 256 + threadIdx.x;
  if (id < NE * KA) {
    int n = id / KA, k = id - n * KA;
    float v = 0.f;
    if (n < 384) {
      int nn = n & 127;
      const float* W = (n < 128) ? Wz : (n < 256) ? Wr : Wh;
      const float* V = (n < 128) ? Vz : (n < 256) ? Vr : Vh;
      if (k < 128)      v = W[nn * 128 + k];
      else if (k < 256) v = V[nn * 128 + (k - 128)];
    } else {
      if (k >= 256) v = Wdgh[(n - 384) * 128 + (k - 256)];
    }
    Wcat[id] = f2bf(v);
  }
  if (id < NE) {
    bias[id] = (id < 128) ? bz[id] : (id < 256) ? br[id - 128]
             : (id < 384) ? bh[id - 256] : bdgh[id - 384];
  }
}

// --------------------------------------------------------------------------
// Fused A-build + GEMM. Tile: M = 16 b x 8 t (b0=(blk&31)*16, t0=(blk>>5)*8),
// N = 512 (full), K = 384 in 12 iters of 32. Tile-local m-row r ->
// (b = b0 + (r&15), t = t0 + (r>>4)). Per iter: ds_read frags -> 32 MFMA ->
// vmcnt(0) [only stage kt+1 loads outstanding] -> convert+ds_write A(kt+1)
// -> barrier -> issue stage kt+2. Staging: srow=tid>>2 (0..127), kq=tid&3.
// kt0-3 load x/m/d/l (non-temporal) and stash mask/delta bf16 in VGPRs;
// kt4-11 reuse stash.
__global__ __launch_bounds__(512, 1) void gemm_fused(
    const float* __restrict__ x, const float* __restrict__ mask,
    const float* __restrict__ delta, const float* __restrict__ xlast,
    const float* __restrict__ xmean,
    const float* __restrict__ wdgx, const float* __restrict__ bdgx,
    const unsigned short* __restrict__ Wcat,
    const float* __restrict__ bias, unsigned short* __restrict__ E)
{
  __shared__ unsigned short As[2][128 * 32];
  __shared__ unsigned short Bs[2][512 * 32];
  const int tid = threadIdx.x;
  const int wave = tid >> 6, lane = tid & 63;
  const int q = lane >> 4, rl = lane & 15;
  const int b0 = (blockIdx.x & 31) * 16;
  const int t0 = (blockIdx.x >> 5) * 8;
  const int blk = b0 >> 4;             // constant per block (E slab index)
  const int wm = (wave >> 2) * 64;     // 2 m-tiles of waves
  const int wn = (wave & 3) * 128;     // 4 n-tiles of waves

  // staging ids: tile row srow -> (b,t)
  const int srow = tid >> 2;           // 0..127 (A-tile row)
  const int kq = tid & 3;              // k-octet within 32
  const int b_g = b0 + (srow & 15);
  const int t_g = t0 + (srow >> 4);
  const size_t xoff = ((size_t)b_g * T_ + t_g) * D_;

  f32x4 acc[4][8];
  #pragma unroll
  for (int a = 0; a < 4; ++a)
    #pragma unroll
    for (int b = 0; b < 8; ++b) acc[a][b] = (f32x4){0.f, 0.f, 0.f, 0.f};

  // in-flight A-stage registers (kt<4 only) + mask/delta bf16 stash
  f32x4 sx0, sx1, sm0, sm1, sd0, sd1, sl0, sl1;
  short8 stM[4], stD[4];

  #define ISSUE_B(kt_, buf_) do {                                             \
    _Pragma("unroll")                                                         \
    for (int i = 0; i < 4; ++i) {                                             \
      int chunk = i * 512 + wave * 64 + lane;                                 \
      int row = chunk >> 2, kc = chunk & 3;                                   \
      ASYNC_CP16(Wcat + (size_t)row * KA + (kt_) * 32 + kc * 8,               \
                 &Bs[buf_][(i * 512 + wave * 64) * 8]);                       \
    }                                                                         \
  } while (0)

  // A loads only exist for kt<4 (x-hat phase); mask/delta come from stash.
  // Non-temporal: 268MB single-use streams must not evict Wcat/E from L2.
  #define ISSUE_A(kt_) do {                                                   \
    int d0 = (kt_) * 32 + kq * 8;                                             \
    sx0 = ldnt4(x + xoff + d0);                                               \
    sx1 = ldnt4(x + xoff + d0 + 4);                                           \
    sm0 = ldnt4(mask + xoff + d0);                                            \
    sm1 = ldnt4(mask + xoff + d0 + 4);                                        \
    sd0 = ldnt4(delta + xoff + d0);                                           \
    sd1 = ldnt4(delta + xoff + d0 + 4);                                       \
    sl0 = ldnt4(xlast + xoff + d0);                                           \
    sl1 = ldnt4(xlast + xoff + d0 + 4);                                       \
  } while (0)

  // x-hat region (kt_ in 0..3): compute xhat, store stash, write LDS
  #define CONVERT_AX(kt_, buf_) do {                                          \
    int d0 = (kt_) * 32 + kq * 8;                                             \
    float U[8], W[8], C[8], X[8], Mm[8], Dd[8], L[8];                         \
    *(float4*)&U[0] = *(const float4*)(xmean + (size_t)b_g * D_ + d0);        \
    *(float4*)&U[4] = *(const float4*)(xmean + (size_t)b_g * D_ + d0 + 4);    \
    *(float4*)&W[0] = *(const float4*)(wdgx + d0);                            \
    *(float4*)&W[4] = *(const float4*)(wdgx + d0 + 4);                        \
    *(float4*)&C[0] = *(const float4*)(bdgx + d0);                            \
    *(float4*)&C[4] = *(const float4*)(bdgx + d0 + 4);                        \
    *(f32x4*)&X[0] = sx0; *(f32x4*)&X[4] = sx1;                               \
    *(f32x4*)&Mm[0] = sm0; *(f32x4*)&Mm[4] = sm1;                             \
    *(f32x4*)&Dd[0] = sd0; *(f32x4*)&Dd[4] = sd1;                             \
    *(f32x4*)&L[0] = sl0; *(f32x4*)&L[4] = sl1;                               \
    short8 ov, mo, dl;                                                        \
    _Pragma("unroll")                                                         \
    for (int i = 0; i < 8; ++i) {                                             \
      float g = __expf(-fmaxf(W[i] * Dd[i] + C[i], 0.f));                     \
      float xh = Mm[i] * X[i] + (1.f - Mm[i]) * (g * L[i] + (1.f - g) * U[i]); \
      ov[i] = (short)f2bf(xh);                                                \
      mo[i] = (short)f2bf(Mm[i]);                                             \
      dl[i] = (short)f2bf(Dd[i]);                                             \
    }                                                                         \
    stM[(kt_)] = mo; stD[(kt_)] = dl;                                         \
    *(short8*)(&As[buf_][srow * 32 + kq * 8]) = ov;                           \
  } while (0)

  // mask region (idx_ = kt_-4 in 0..3): replay stash
  #define CONVERT_AM(idx_, buf_) do {                                         \
    short8 ov = stM[(idx_)];                                                  \
    *(short8*)(&As[buf_][srow * 32 + kq * 8]) = ov;                           \
  } while (0)

  // delta region (idx_ = kt_-8 in 0..3): replay stash
  #define CONVERT_AD(idx_, buf_) do {                                         \
    short8 ov = stD[(idx_)];                                                  \
    *(short8*)(&As[buf_][srow * 32 + kq * 8]) = ov;                           \
  } while (0)

  // ---- prologue: stage 0 synchronously, stage 1 in flight ----
  ISSUE_A(0); ISSUE_B(0, 0);
  asm volatile("s_waitcnt vmcnt(0)" ::: "memory");
  CONVERT_AX(0, 0);
  BAR_LDS();
  ISSUE_A(1); ISSUE_B(1, 1);

  #pragma unroll
  for (int kt = 0; kt < 12; ++kt) {
    const int cur = kt & 1;
    short8 af[4];
    #pragma unroll
    for (int tm = 0; tm < 4; ++tm)
      af[tm] = *(const short8*)(&As[cur][(wm + tm * 16 + rl) * 32 + q * 8]);
    // split B-frag reads into 2 halves of 4 (register pressure)
    #pragma unroll
    for (int half = 0; half < 2; ++half) {
      short8 bfr[4];
      #pragma unroll
      for (int j = 0; j < 4; ++j)
        bfr[j] = *(const short8*)(&Bs[cur][(wn + (half * 4 + j) * 16 + rl) * 32 + q * 8]);
      #pragma unroll
      for (int tm = 0; tm < 4; ++tm)
        #pragma unroll
        for (int j = 0; j < 4; ++j)
          acc[tm][half * 4 + j] =
            __builtin_amdgcn_mfma_f32_16x16x32_bf16(af[tm], bfr[j], acc[tm][half * 4 + j], 0, 0, 0);
    }
    if (kt < 11) {
      // only stage kt+1's loads are outstanding here -> vmcnt(0) is exact
      asm volatile("s_waitcnt vmcnt(0)" ::: "memory");
      if (kt == 0)      CONVERT_AX(1, 1);
      else if (kt == 1) CONVERT_AX(2, 0);
      else if (kt == 2) CONVERT_AX(3, 1);
      else if (kt == 3) CONVERT_AM(0, 0);
      else if (kt == 4) CONVERT_AM(1, 1);
      else if (kt == 5) CONVERT_AM(2, 0);
      else if (kt == 6) CONVERT_AM(3, 1);
      else if (kt == 7) CONVERT_AD(0, 0);
      else if (kt == 8) CONVERT_AD(1, 1);
      else if (kt == 9) CONVERT_AD(2, 0);
      else              CONVERT_AD(3, 1);
      BAR_LDS();   // As/Bs[cur^1] complete; all waves done reading [cur]
      if (kt < 10) {
        if (kt == 0)      { ISSUE_A(2); ISSUE_B(2, 0); }
        else if (kt == 1) { ISSUE_A(3); ISSUE_B(3, 1); }
        else if (kt == 2) { ISSUE_B(4, 0); }
        else if (kt == 3) { ISSUE_B(5, 1); }
        else if (kt == 4) { ISSUE_B(6, 0); }
        else if (kt == 5) { ISSUE_B(7, 1); }
        else if (kt == 6) { ISSUE_B(8, 0); }
        else if (kt == 7) { ISSUE_B(9, 1); }
        else if (kt == 8) { ISSUE_B(10, 0); }
        else              { ISSUE_B(11, 1); }
      }
    }
  }
  #undef ISSUE_A
  #undef ISSUE_B
  #undef CONVERT_AX
  #undef CONVERT_AM
  #undef CONVERT_AD

  // epilogue: write E in block-local scan layout E[t][b>>4][n][b&15].
  // tile row group tm -> t = t0 + (wm>>4) + tm; C-row q*4+reg = b&15.
  #pragma unroll
  for (int tn = 0; tn < 8; ++tn) {
    int n = wn + tn * 16 + rl;
    float bv = bias[n];
    bool isg = (n >= 384);
    #pragma unroll
    for (int tm = 0; tm < 4; ++tm) {
      int t = t0 + (wm >> 4) + tm;
      float v[4];
      #pragma unroll
      for (int reg = 0; reg < 4; ++reg) {
        float xv = acc[tm][tn][reg] + bv;
        v[reg] = isg ? __expf(-fmaxf(xv, 0.f)) : xv;
      }
      st4(E + ((size_t)t * 32 + blk) * ESLAB + (size_t)n * 16 + q * 4, v);
    }
  }
}

// --------------------------------------------------------------------------
// Scan (round-0 version, best measured 212us): 32 blocks x 16 batch rows,
// 8 waves x 16 H-cols; vectorized E loads prefetched one step ahead; raw
// lgkm-only barriers; rcp-based sigmoid/tanh; classifier fused.
__global__ __launch_bounds__(512, 2) void grud_scan(
    const unsigned short* __restrict__ E,
    const float* __restrict__ Uz, const float* __restrict__ Ur, const float* __restrict__ Uh,
    const float* __restrict__ hs0, const float* __restrict__ statics,
    const float* __restrict__ Wout, const float* __restrict__ bout,
    float* __restrict__ out)
{
  __shared__ unsigned short hdec[16 * HP];
  __shared__ unsigned short rhb[16 * HP];
  __shared__ float hfin[16 * HP];
  const int tid = threadIdx.x;
  const int wave = tid >> 6, lane = tid & 63;
  const int q = lane >> 4, rl = lane & 15;
  const int col = wave * 16 + rl;       // H column this lane owns (C/D + B-frag)
  const int b0 = blockIdx.x * 16;

  // U_* as resident B-fragments: B[k][n]=U[n][k]; lane: n=col, k=kc*32+q*8+j
  short8 uz[4], ur[4], uh[4];
  #pragma unroll
  for (int kc = 0; kc < 4; ++kc) {
    int koff = kc * 32 + q * 8;
    const float* pzw = Uz + col * H_ + koff;
    const float* prw = Ur + col * H_ + koff;
    const float* phw = Uh + col * H_ + koff;
    #pragma unroll
    for (int j = 0; j < 8; ++j) {
      uz[kc][j] = (short)f2bf(pzw[j]);
      ur[kc][j] = (short)f2bf(prw[j]);
      uh[kc][j] = (short)f2bf(phw[j]);
    }
  }

  // per-lane E pointers (block-local layout): slab = blk*ESLAB, +n*16 + q*4
  const unsigned short* pz = E + (size_t)blockIdx.x * ESLAB + (size_t)col * 16 + q * 4;
  const unsigned short* pr = pz + 128 * 16;
  const unsigned short* ph = pz + 256 * 16;
  const unsigned short* pg = pz + 384 * 16;

  uint2 cz, cr, chh, cg, nz{}, nr{}, nh{}, ng{};
  cz  = ldraw(pz);                 // slab t=0
  cr  = ldraw(pr);
  chh = ldraw(ph);
  cg  = ldraw(pg + ESTRIDE);       // gamma for step 0's epilogue = slab 1
  uint2 g0raw = ldraw(pg);         // gamma at t=0 for h-init

  // h state (fp32) in C/D layout: rows q*4+reg, col
  float hd[4], g0[4];
  unp(g0raw, g0);
  #pragma unroll
  for (int reg = 0; reg < 4; ++reg) {
    int row = q * 4 + reg;
    float h0 = hs0[(b0 + row) * H_ + col];
    hd[reg] = g0[reg] * h0;
    hdec[row * HP + col] = f2bf_fast(hd[reg]);
  }
  BAR_LDS();

  for (int t = 0; t < T_; ++t) {
    // ---- prefetch E for step t+1 (and gamma for t+2) ----
    if (t + 1 < T_) {
      size_t off = (size_t)(t + 1) * ESTRIDE;
      nz = ldraw(pz + off); nr = ldraw(pr + off); nh = ldraw(ph + off);
      if (t + 2 < T_) ng = ldraw(pg + (size_t)(t + 2) * ESTRIDE);
    }
    float Pz[4], Pr[4], Ph[4];
    unp(cz, Pz); unp(cr, Pr); unp(chh, Ph);

    // A-frags of decayed h from LDS
    short8 af[4];
    #pragma unroll
    for (int kc = 0; kc < 4; ++kc)
      af[kc] = *(const short8*)(&hdec[rl * HP + kc * 32 + q * 8]);
    f32x4 accz = (f32x4){0.f,0.f,0.f,0.f}, accr = (f32x4){0.f,0.f,0.f,0.f};
    #pragma unroll
    for (int kc = 0; kc < 4; ++kc) {
      accz = __builtin_amdgcn_mfma_f32_16x16x32_bf16(af[kc], uz[kc], accz, 0, 0, 0);
      accr = __builtin_amdgcn_mfma_f32_16x16x32_bf16(af[kc], ur[kc], accr, 0, 0, 0);
    }
    float zz[4];
    #pragma unroll
    for (int reg = 0; reg < 4; ++reg) {
      zz[reg] = fsigmoid(accz[reg] + Pz[reg]);
      float rr = fsigmoid(accr[reg] + Pr[reg]);
      rhb[(q * 4 + reg) * HP + col] = f2bf_fast(rr * hd[reg]);
    }
    BAR_LDS();                                         // barrier 1

    short8 ar[4];
    #pragma unroll
    for (int kc = 0; kc < 4; ++kc)
      ar[kc] = *(const short8*)(&rhb[rl * HP + kc * 32 + q * 8]);
    f32x4 acch = (f32x4){0.f,0.f,0.f,0.f};
    #pragma unroll
    for (int kc = 0; kc < 4; ++kc)
      acch = __builtin_amdgcn_mfma_f32_16x16x32_bf16(ar[kc], uh[kc], acch, 0, 0, 0);

    if (t < T_ - 1) {
      float Gn[4];
      unp(cg, Gn);
      #pragma unroll
      for (int reg = 0; reg < 4; ++reg) {
        float ht = ftanh(acch[reg] + Ph[reg]);
        float hn = hd[reg] + zz[reg] * (ht - hd[reg]);   // (1-z)h + z*h~
        hd[reg] = Gn[reg] * hn;                          // fold next-step decay
        hdec[(q * 4 + reg) * HP + col] = f2bf_fast(hd[reg]);
      }
    } else {
      #pragma unroll
      for (int reg = 0; reg < 4; ++reg) {
        float ht = ftanh(acch[reg] + Ph[reg]);
        float hn = hd[reg] + zz[reg] * (ht - hd[reg]);
        hfin[(q * 4 + reg) * HP + col] = hn;
      }
    }
    BAR_LDS();                                         // barrier 2

    cz = nz; cr = nr; chh = nh; cg = ng;
  }

  // fused classifier: 32 threads per batch row
  {
    int row = tid >> 5, j = tid & 31;
    float acc = 0.f;
    #pragma unroll
    for (int c0 = 0; c0 < 4; ++c0)
      acc += hfin[row * HP + j + c0 * 32] * Wout[j + c0 * 32];
    acc += statics[(size_t)(b0 + row) * S_ + j] * Wout[H_ + j];
    #pragma unroll
    for (int off = 16; off >= 1; off >>= 1)
      acc += __shfl_down(acc, off, 32);
    if (j == 0) out[b0 + row] = acc + bout[0];
  }
}

// --------------------------------------------------------------------------
static void launch_all(void* const* d_in, float* out, char* ws, hipStream_t stream)
{
  const float* x      = (const float*)d_in[0];
  const float* statics= (const float*)d_in[1];
  const float* mask   = (const float*)d_in[2];
  const float* delta  = (const float*)d_in[3];
  const float* xlast  = (const float*)d_in[4];
  const float* xmean  = (const float*)d_in[5];
  const float* hs0    = (const float*)d_in[6];
  const float* wdgx   = (const float*)d_in[7];
  const float* bdgx   = (const float*)d_in[8];
  const float* Wdgh   = (const float*)d_in[9];
  const float* bdgh   = (const float*)d_in[10];
  const float* Wz     = (const float*)d_in[11];
  const float* Uz     = (const float*)d_in[12];
  const float* Vz     = (const float*)d_in[13];
  const float* bz     = (const float*)d_in[14];
  const float* Wr     = (const float*)d_in[15];
  const float* Ur     = (const float*)d_in[16];
  const float* Vr     = (const float*)d_in[17];
  const float* br     = (const float*)d_in[18];
  const float* Wh     = (const float*)d_in[19];
  const float* Uh     = (const float*)d_in[20];
  const float* Vh     = (const float*)d_in[21];
  const float* bh     = (const float*)d_in[22];
  const float* Wout   = (const float*)d_in[23];
  const float* bout   = (const float*)d_in[24];

  const size_t eBytes = (size_t)M_ * NE * 2;          // bf16 E, always
  const size_t wBytes = (size_t)NE * KA * 2;
  unsigned short* E = (unsigned short*)ws;
  unsigned short* Wcat = (unsigned short*)(ws + eBytes);
  float* bias = (float*)(ws + eBytes + wBytes);

  prep_weights<<<768, 256, 0, stream>>>(Wz, Vz, Wr, Vr, Wh, Vh, Wdgh,
                                        bz, br, bh, bdgh, Wcat, bias);
  gemm_fused<<<M_ / 128, 512, 0, stream>>>(x, mask, delta, xlast, xmean,
                                           wdgx, bdgx, Wcat, bias, E);
  grud_scan<<<B_ / 16, 512, 0, stream>>>(E, Uz, Ur, Uh, hs0, statics, Wout, bout, out);
}

extern "C" void kernel_launch(void* const* d_in, const int* in_sizes, int n_in,
                              void* d_out, int out_size, void* d_ws, size_t ws_size,
                              hipStream_t stream)
{
  char* ws = (char*)d_ws;
  float* out = (float*)d_out;
  const size_t needBF = (size_t)M_ * NE * 2 + (size_t)NE * KA * 2 + 8192;  // ~135 MB
  if (ws_size >= needBF) launch_all(d_in, out, ws, stream);
  // else: workspace too small — launch nothing (fails visibly)
}

// Round 11
// 517.641 us; speedup vs baseline: 1.1280x; 1.0555x over previous
//
#include <hip/hip_runtime.h>
#include <stdint.h>

// ---------------------------------------------------------------------------
// GRU-D (MIMIC) forward. B=512, T=256, D=128, H=128, S=32.
// Phase 0 : pack weights Wcat_t[n][k] bf16 + bias[512]
// Phase 1 : gemm_fused: E = A @ Wcat^T with A built ON THE FLY.
//           BM=128 (16b x 8t), 512 thr, NT input loads (r10: -21us).
//           ROUND 11: exploit Wcat block-sparsity. Wcat zeros: n<384 has
//           k in [256,384) == 0; n>=384 has k<256 == 0. Old kernel did
//           12kt x 512n = 384 MFMA/block; useful = 58%. Split:
//             phase 1 (kt 0-7, xhat|mask): n < 384 only -> 24 MFMA/kt
//             phase 2 (kt 8-11, delta):    n in [384,512) -> 8 MFMA/kt
//           = 224 MFMA/block (-42%), B-staging -42%, same A staging,
//           same pipeline schedule, bit-identical E (skipped products = 0).
//           E ALWAYS bf16 (r5 lesson). E[t][blk=b>>4][n(512)][b&15].
// Phase 2 : sequential scan (r0 verbatim, 212-214us local optimum --
//           pinned across 10 rounds; VALU/latency-bound at the structural
//           32-CU cap; r1/r2/r3 falsified all alternative structures).
// LESSONS: r1 fewer waves = regression. r2 conflict-free LDS = null.
//   r3 2 groups/block = regression (CU cap). r4 128x256 tile: -31us.
//   r5 f32-E ws-threshold bug: +108us. r6 fused producer: 567.9.
//   r7 NT-stores on cache-communicated intermediates: regression.
//   r8/r9 compile errors: no OOB constant indices even in dead code;
//   NT builtins need ext_vector types. r10 NT input loads: -21.5us (546.4).
// ---------------------------------------------------------------------------

#define B_ 512
#define T_ 256
#define D_ 128
#define H_ 128
#define S_ 32
#define NE 512   // E width: z(128) r(128) h(128) gamma(128)
#define KA 384   // A width: xhat(128) mask(128) delta(128)
#define M_ (B_*T_)
#define HP 136   // padded LDS row stride (shorts / floats)
#define ESLAB ((size_t)NE * 16)        // elements per (t,blk) slab = 8192
#define ESTRIDE ((size_t)32 * ESLAB)   // elements per t = 262144

typedef __attribute__((ext_vector_type(8))) short short8;
typedef __attribute__((ext_vector_type(4))) float f32x4;

// raw barrier: LDS visibility only (lgkm drain), no vmcnt(0) drain of
// in-flight global prefetches (which __syncthreads would force).
#define BAR_LDS() asm volatile("s_waitcnt lgkmcnt(0)\n\ts_barrier" ::: "memory")

__device__ __forceinline__ unsigned short f2bf(float f) {
  union { float f; uint32_t u; } v; v.f = f;
  return (unsigned short)((v.u + 0x7FFFu + ((v.u >> 16) & 1u)) >> 16);
}
// cheap round-half-up bf16 (2 VALU ops) — scan LDS stores only
__device__ __forceinline__ unsigned short f2bf_fast(float f) {
  union { float f; uint32_t u; } v; v.f = f;
  return (unsigned short)((v.u + 0x8000u) >> 16);
}
__device__ __forceinline__ float bf2f(uint32_t s) {
  union { uint32_t u; float f; } v; v.u = s << 16;
  return v.f;
}

__device__ __forceinline__ uint2 ldraw(const unsigned short* p) { return *(const uint2*)p; }
__device__ __forceinline__ void unp(uint2 v, float o[4]) {
  o[0] = bf2f(v.x & 0xffffu); o[1] = bf2f(v.x >> 16);
  o[2] = bf2f(v.y & 0xffffu); o[3] = bf2f(v.y >> 16);
}
__device__ __forceinline__ void st4(unsigned short* p, const float v[4]) {
  uint2 u;
  u.x = (uint32_t)f2bf(v[0]) | ((uint32_t)f2bf(v[1]) << 16);
  u.y = (uint32_t)f2bf(v[2]) | ((uint32_t)f2bf(v[3]) << 16);
  *(uint2*)p = u;
}

__device__ __forceinline__ float fsigmoid(float x) {
  return __builtin_amdgcn_rcpf(1.f + __expf(-x));
}
__device__ __forceinline__ float ftanh(float x) {
  return 1.f - 2.f * __builtin_amdgcn_rcpf(1.f + __expf(2.f * x));
}

// non-temporal 16B load (single-use streams; no L2 allocate).
// Requires NATIVE vector type (ext_vector), not HIP float4 (r9 lesson).
__device__ __forceinline__ f32x4 ldnt4(const float* p) {
  return __builtin_nontemporal_load((const f32x4*)p);
}

#define ASYNC_CP16(gsrc, ldst) \
  __builtin_amdgcn_global_load_lds((const __attribute__((address_space(1))) void*)(gsrc), \
                                   (__attribute__((address_space(3))) void*)(ldst), 16, 0, 0)

// --------------------------------------------------------------------------
__global__ void prep_weights(const float* __restrict__ Wz, const float* __restrict__ Vz,
                             const float* __restrict__ Wr, const float* __restrict__ Vr,
                             const float* __restrict__ Wh, const float* __restrict__ Vh,
                             const float* __restrict__ Wdgh,
                             const float* __restrict__ bz, const float* __restrict__ br,
                             const float* __restrict__ bh, const float* __restrict__ bdgh,
                             unsigned short* __restrict__ Wcat, float* __restrict__ bias)
{
  int id = blockIdx.x * 256 + threadIdx.x;
  if (id < NE * KA) {
    int n = id / KA, k = id - n * KA;
    float v = 0.f;
    if (n < 384) {
      int nn = n & 127;
      const float* W = (n < 128) ? Wz : (n < 256) ? Wr : Wh;
      const float* V = (n < 128) ? Vz : (n < 256) ? Vr : Vh;
      if (k < 128)      v = W[nn * 128 + k];
      else if (k < 256) v = V[nn * 128 + (k - 128)];
    } else {
      if (k >= 256) v = Wdgh[(n - 384) * 128 + (k - 256)];
    }
    Wcat[id] = f2bf(v);
  }
  if (id < NE) {
    bias[id] = (id < 128) ? bz[id] : (id < 256) ? br[id - 128]
             : (id < 384) ? bh[id - 256] : bdgh[id - 384];
  }
}

// --------------------------------------------------------------------------
// Fused A-build + GEMM with sparsity-split N. Tile: M = 16 b x 8 t,
// K = 384 in 12 iters of 32. kt 0-7: N=[0,384) (xhat|mask K-region);
// kt 8-11: N=[384,512) (delta K-region -> gamma cols). Per iter:
// ds_read frags -> MFMA -> vmcnt(0) [only stage kt+1 outstanding] ->
// convert+ds_write A(kt+1) -> barrier -> issue stage kt+2.
// Staging: srow=tid>>2 (0..127), kq=tid&3. kt0-3 load x/m/d/l (NT) and
// stash mask/delta bf16 in VGPRs; kt4-11 reuse stash.
__global__ __launch_bounds__(512, 1) void gemm_fused(
    const float* __restrict__ x, const float* __restrict__ mask,
    const float* __restrict__ delta, const float* __restrict__ xlast,
    const float* __restrict__ xmean,
    const float* __restrict__ wdgx, const float* __restrict__ bdgx,
    const unsigned short* __restrict__ Wcat,
    const float* __restrict__ bias, unsigned short* __restrict__ E)
{
  __shared__ unsigned short As[2][128 * 32];
  __shared__ unsigned short Bs[2][384 * 32];   // phase-1 needs 384 rows max
  const int tid = threadIdx.x;
  const int wave = tid >> 6, lane = tid & 63;
  const int q = lane >> 4, rl = lane & 15;
  const int b0 = (blockIdx.x & 31) * 16;
  const int t0 = (blockIdx.x >> 5) * 8;
  const int blk = b0 >> 4;             // constant per block (E slab index)
  const int wm = (wave >> 2) * 64;     // 2 m-groups of waves
  const int wng = wave & 3;            // n-group: phase1 96 cols, phase2 32

  // staging ids: tile row srow -> (b,t)
  const int srow = tid >> 2;           // 0..127 (A-tile row)
  const int kq = tid & 3;              // k-octet within 32
  const int b_g = b0 + (srow & 15);
  const int t_g = t0 + (srow >> 4);
  const size_t xoff = ((size_t)b_g * T_ + t_g) * D_;

  f32x4 acc[4][6];    // phase-1 accumulators: n = wng*96 + tn*16 + rl
  f32x4 accg[4][2];   // phase-2 (gamma): n = 384 + wng*32 + tn*16 + rl
  #pragma unroll
  for (int a = 0; a < 4; ++a) {
    #pragma unroll
    for (int b = 0; b < 6; ++b) acc[a][b] = (f32x4){0.f, 0.f, 0.f, 0.f};
    accg[a][0] = (f32x4){0.f, 0.f, 0.f, 0.f};
    accg[a][1] = (f32x4){0.f, 0.f, 0.f, 0.f};
  }

  // in-flight A-stage registers (kt<4 only) + mask/delta bf16 stash
  f32x4 sx0, sx1, sm0, sm1, sd0, sd1, sl0, sl1;
  short8 stM[4], stD[4];

  // B staging: kt<8 -> rows 0..383 (3 loads/thread); kt>=8 -> Wcat rows
  // 384..511 into Bs rows 0..127 (1 load/thread).
  #define ISSUE_B(kt_, buf_) do {                                             \
    if ((kt_) < 8) {                                                          \
      _Pragma("unroll")                                                       \
      for (int i = 0; i < 3; ++i) {                                           \
        int chunk = i * 512 + tid;                                            \
        int row = chunk >> 2, kc = chunk & 3;                                 \
        ASYNC_CP16(Wcat + (size_t)row * KA + (kt_) * 32 + kc * 8,             \
                   &Bs[buf_][chunk * 8]);                                     \
      }                                                                       \
    } else {                                                                  \
      int row = tid >> 2, kc = tid & 3;                                       \
      ASYNC_CP16(Wcat + (size_t)(384 + row) * KA + (kt_) * 32 + kc * 8,       \
                 &Bs[buf_][tid * 8]);                                         \
    }                                                                         \
  } while (0)

  // A loads only exist for kt<4; NT (268MB single-use; keep L2 for Wcat/E)
  #define ISSUE_A(kt_) do {                                                   \
    int d0 = (kt_) * 32 + kq * 8;                                             \
    sx0 = ldnt4(x + xoff + d0);                                               \
    sx1 = ldnt4(x + xoff + d0 + 4);                                           \
    sm0 = ldnt4(mask + xoff + d0);                                            \
    sm1 = ldnt4(mask + xoff + d0 + 4);                                        \
    sd0 = ldnt4(delta + xoff + d0);                                           \
    sd1 = ldnt4(delta + xoff + d0 + 4);                                       \
    sl0 = ldnt4(xlast + xoff + d0);                                           \
    sl1 = ldnt4(xlast + xoff + d0 + 4);                                       \
  } while (0)

  // x-hat region (kt_ in 0..3): compute xhat, store stash, write LDS
  #define CONVERT_AX(kt_, buf_) do {                                          \
    int d0 = (kt_) * 32 + kq * 8;                                             \
    float U[8], W[8], C[8], X[8], Mm[8], Dd[8], L[8];                         \
    *(float4*)&U[0] = *(const float4*)(xmean + (size_t)b_g * D_ + d0);        \
    *(float4*)&U[4] = *(const float4*)(xmean + (size_t)b_g * D_ + d0 + 4);    \
    *(float4*)&W[0] = *(const float4*)(wdgx + d0);                            \
    *(float4*)&W[4] = *(const float4*)(wdgx + d0 + 4);                        \
    *(float4*)&C[0] = *(const float4*)(bdgx + d0);                            \
    *(float4*)&C[4] = *(const float4*)(bdgx + d0 + 4);                        \
    *(f32x4*)&X[0] = sx0; *(f32x4*)&X[4] = sx1;                               \
    *(f32x4*)&Mm[0] = sm0; *(f32x4*)&Mm[4] = sm1;                             \
    *(f32x4*)&Dd[0] = sd0; *(f32x4*)&Dd[4] = sd1;                             \
    *(f32x4*)&L[0] = sl0; *(f32x4*)&L[4] = sl1;                               \
    short8 ov, mo, dl;                                                        \
    _Pragma("unroll")                                                         \
    for (int i = 0; i < 8; ++i) {                                             \
      float g = __expf(-fmaxf(W[i] * Dd[i] + C[i], 0.f));                     \
      float xh = Mm[i] * X[i] + (1.f - Mm[i]) * (g * L[i] + (1.f - g) * U[i]); \
      ov[i] = (short)f2bf(xh);                                                \
      mo[i] = (short)f2bf(Mm[i]);                                             \
      dl[i] = (short)f2bf(Dd[i]);                                             \
    }                                                                         \
    stM[(kt_)] = mo; stD[(kt_)] = dl;                                         \
    *(short8*)(&As[buf_][srow * 32 + kq * 8]) = ov;                           \
  } while (0)

  // mask region (idx_ = kt_-4 in 0..3): replay stash
  #define CONVERT_AM(idx_, buf_) do {                                         \
    short8 ov = stM[(idx_)];                                                  \
    *(short8*)(&As[buf_][srow * 32 + kq * 8]) = ov;                           \
  } while (0)

  // delta region (idx_ = kt_-8 in 0..3): replay stash
  #define CONVERT_AD(idx_, buf_) do {                                         \
    short8 ov = stD[(idx_)];                                                  \
    *(short8*)(&As[buf_][srow * 32 + kq * 8]) = ov;                           \
  } while (0)

  // ---- prologue: stage 0 synchronously, stage 1 in flight ----
  ISSUE_A(0); ISSUE_B(0, 0);
  asm volatile("s_waitcnt vmcnt(0)" ::: "memory");
  CONVERT_AX(0, 0);
  BAR_LDS();
  ISSUE_A(1); ISSUE_B(1, 1);

  #pragma unroll
  for (int kt = 0; kt < 12; ++kt) {
    const int cur = kt & 1;
    short8 af[4];
    #pragma unroll
    for (int tm = 0; tm < 4; ++tm)
      af[tm] = *(const short8*)(&As[cur][(wm + tm * 16 + rl) * 32 + q * 8]);
    if (kt < 8) {
      // phase 1: 6 n-tiles (n = wng*96 + tn*16), 24 MFMA, split 3+3
      #pragma unroll
      for (int half = 0; half < 2; ++half) {
        short8 bfr[3];
        #pragma unroll
        for (int j = 0; j < 3; ++j)
          bfr[j] = *(const short8*)(&Bs[cur][(wng * 96 + (half * 3 + j) * 16 + rl) * 32 + q * 8]);
        #pragma unroll
        for (int tm = 0; tm < 4; ++tm)
          #pragma unroll
          for (int j = 0; j < 3; ++j)
            acc[tm][half * 3 + j] =
              __builtin_amdgcn_mfma_f32_16x16x32_bf16(af[tm], bfr[j], acc[tm][half * 3 + j], 0, 0, 0);
      }
    } else {
      // phase 2: 2 n-tiles (Bs rows wng*32 + tn*16), 8 MFMA
      short8 bfr[2];
      bfr[0] = *(const short8*)(&Bs[cur][(wng * 32 + rl) * 32 + q * 8]);
      bfr[1] = *(const short8*)(&Bs[cur][(wng * 32 + 16 + rl) * 32 + q * 8]);
      #pragma unroll
      for (int tm = 0; tm < 4; ++tm) {
        accg[tm][0] = __builtin_amdgcn_mfma_f32_16x16x32_bf16(af[tm], bfr[0], accg[tm][0], 0, 0, 0);
        accg[tm][1] = __builtin_amdgcn_mfma_f32_16x16x32_bf16(af[tm], bfr[1], accg[tm][1], 0, 0, 0);
      }
    }
    if (kt < 11) {
      // only stage kt+1's loads are outstanding here -> vmcnt(0) is exact
      asm volatile("s_waitcnt vmcnt(0)" ::: "memory");
      if (kt == 0)      CONVERT_AX(1, 1);
      else if (kt == 1) CONVERT_AX(2, 0);
      else if (kt == 2) CONVERT_AX(3, 1);
      else if (kt == 3) CONVERT_AM(0, 0);
      else if (kt == 4) CONVERT_AM(1, 1);
      else if (kt == 5) CONVERT_AM(2, 0);
      else if (kt == 6) CONVERT_AM(3, 1);
      else if (kt == 7) CONVERT_AD(0, 0);
      else if (kt == 8) CONVERT_AD(1, 1);
      else if (kt == 9) CONVERT_AD(2, 0);
      else              CONVERT_AD(3, 1);
      BAR_LDS();   // As/Bs[cur^1] complete; all waves done reading [cur]
      if (kt < 10) {
        if (kt == 0)      { ISSUE_A(2); ISSUE_B(2, 0); }
        else if (kt == 1) { ISSUE_A(3); ISSUE_B(3, 1); }
        else if (kt == 2) { ISSUE_B(4, 0); }
        else if (kt == 3) { ISSUE_B(5, 1); }
        else if (kt == 4) { ISSUE_B(6, 0); }
        else if (kt == 5) { ISSUE_B(7, 1); }
        else if (kt == 6) { ISSUE_B(8, 0); }
        else if (kt == 7) { ISSUE_B(9, 1); }
        else if (kt == 8) { ISSUE_B(10, 0); }
        else              { ISSUE_B(11, 1); }
      }
    }
  }
  #undef ISSUE_A
  #undef ISSUE_B
  #undef CONVERT_AX
  #undef CONVERT_AM
  #undef CONVERT_AD

  // epilogue: write E in block-local scan layout E[t][b>>4][n][b&15].
  // tile row group tm -> t = t0 + (wm>>4) + tm; C-row q*4+reg = b&15.
  // phase-1 cols (n < 384): bias only.
  #pragma unroll
  for (int tn = 0; tn < 6; ++tn) {
    int n = wng * 96 + tn * 16 + rl;
    float bv = bias[n];
    #pragma unroll
    for (int tm = 0; tm < 4; ++tm) {
      int t = t0 + (wm >> 4) + tm;
      float v[4];
      #pragma unroll
      for (int reg = 0; reg < 4; ++reg) v[reg] = acc[tm][tn][reg] + bv;
      st4(E + ((size_t)t * 32 + blk) * ESLAB + (size_t)n * 16 + q * 4, v);
    }
  }
  // phase-2 cols (n >= 384): bias + exp(-relu)
  #pragma unroll
  for (int tn = 0; tn < 2; ++tn) {
    int n = 384 + wng * 32 + tn * 16 + rl;
    float bv = bias[n];
    #pragma unroll
    for (int tm = 0; tm < 4; ++tm) {
      int t = t0 + (wm >> 4) + tm;
      float v[4];
      #pragma unroll
      for (int reg = 0; reg < 4; ++reg)
        v[reg] = __expf(-fmaxf(accg[tm][tn][reg] + bv, 0.f));
      st4(E + ((size_t)t * 32 + blk) * ESLAB + (size_t)n * 16 + q * 4, v);
    }
  }
}

// --------------------------------------------------------------------------
// Scan (round-0 version, best measured 212us): 32 blocks x 16 batch rows,
// 8 waves x 16 H-cols; vectorized E loads prefetched one step ahead; raw
// lgkm-only barriers; rcp-based sigmoid/tanh; classifier fused.
__global__ __launch_bounds__(512, 2) void grud_scan(
    const unsigned short* __restrict__ E,
    const float* __restrict__ Uz, const float* __restrict__ Ur, const float* __restrict__ Uh,
    const float* __restrict__ hs0, const float* __restrict__ statics,
    const float* __restrict__ Wout, const float* __restrict__ bout,
    float* __restrict__ out)
{
  __shared__ unsigned short hdec[16 * HP];
  __shared__ unsigned short rhb[16 * HP];
  __shared__ float hfin[16 * HP];
  const int tid = threadIdx.x;
  const int wave = tid >> 6, lane = tid & 63;
  const int q = lane >> 4, rl = lane & 15;
  const int col = wave * 16 + rl;       // H column this lane owns (C/D + B-frag)
  const int b0 = blockIdx.x * 16;

  // U_* as resident B-fragments: B[k][n]=U[n][k]; lane: n=col, k=kc*32+q*8+j
  short8 uz[4], ur[4], uh[4];
  #pragma unroll
  for (int kc = 0; kc < 4; ++kc) {
    int koff = kc * 32 + q * 8;
    const float* pzw = Uz + col * H_ + koff;
    const float* prw = Ur + col * H_ + koff;
    const float* phw = Uh + col * H_ + koff;
    #pragma unroll
    for (int j = 0; j < 8; ++j) {
      uz[kc][j] = (short)f2bf(pzw[j]);
      ur[kc][j] = (short)f2bf(prw[j]);
      uh[kc][j] = (short)f2bf(phw[j]);
    }
  }

  // per-lane E pointers (block-local layout): slab = blk*ESLAB, +n*16 + q*4
  const unsigned short* pz = E + (size_t)blockIdx.x * ESLAB + (size_t)col * 16 + q * 4;
  const unsigned short* pr = pz + 128 * 16;
  const unsigned short* ph = pz + 256 * 16;
  const unsigned short* pg = pz + 384 * 16;

  uint2 cz, cr, chh, cg, nz{}, nr{}, nh{}, ng{};
  cz  = ldraw(pz);                 // slab t=0
  cr  = ldraw(pr);
  chh = ldraw(ph);
  cg  = ldraw(pg + ESTRIDE);       // gamma for step 0's epilogue = slab 1
  uint2 g0raw = ldraw(pg);         // gamma at t=0 for h-init

  // h state (fp32) in C/D layout: rows q*4+reg, col
  float hd[4], g0[4];
  unp(g0raw, g0);
  #pragma unroll
  for (int reg = 0; reg < 4; ++reg) {
    int row = q * 4 + reg;
    float h0 = hs0[(b0 + row) * H_ + col];
    hd[reg] = g0[reg] * h0;
    hdec[row * HP + col] = f2bf_fast(hd[reg]);
  }
  BAR_LDS();

  for (int t = 0; t < T_; ++t) {
    // ---- prefetch E for step t+1 (and gamma for t+2) ----
    if (t + 1 < T_) {
      size_t off = (size_t)(t + 1) * ESTRIDE;
      nz = ldraw(pz + off); nr = ldraw(pr + off); nh = ldraw(ph + off);
      if (t + 2 < T_) ng = ldraw(pg + (size_t)(t + 2) * ESTRIDE);
    }
    float Pz[4], Pr[4], Ph[4];
    unp(cz, Pz); unp(cr, Pr); unp(chh, Ph);

    // A-frags of decayed h from LDS
    short8 af[4];
    #pragma unroll
    for (int kc = 0; kc < 4; ++kc)
      af[kc] = *(const short8*)(&hdec[rl * HP + kc * 32 + q * 8]);
    f32x4 accz = (f32x4){0.f,0.f,0.f,0.f}, accr = (f32x4){0.f,0.f,0.f,0.f};
    #pragma unroll
    for (int kc = 0; kc < 4; ++kc) {
      accz = __builtin_amdgcn_mfma_f32_16x16x32_bf16(af[kc], uz[kc], accz, 0, 0, 0);
      accr = __builtin_amdgcn_mfma_f32_16x16x32_bf16(af[kc], ur[kc], accr, 0, 0, 0);
    }
    float zz[4];
    #pragma unroll
    for (int reg = 0; reg < 4; ++reg) {
      zz[reg] = fsigmoid(accz[reg] + Pz[reg]);
      float rr = fsigmoid(accr[reg] + Pr[reg]);
      rhb[(q * 4 + reg) * HP + col] = f2bf_fast(rr * hd[reg]);
    }
    BAR_LDS();                                         // barrier 1

    short8 ar[4];
    #pragma unroll
    for (int kc = 0; kc < 4; ++kc)
      ar[kc] = *(const short8*)(&rhb[rl * HP + kc * 32 + q * 8]);
    f32x4 acch = (f32x4){0.f,0.f,0.f,0.f};
    #pragma unroll
    for (int kc = 0; kc < 4; ++kc)
      acch = __builtin_amdgcn_mfma_f32_16x16x32_bf16(ar[kc], uh[kc], acch, 0, 0, 0);

    if (t < T_ - 1) {
      float Gn[4];
      unp(cg, Gn);
      #pragma unroll
      for (int reg = 0; reg < 4; ++reg) {
        float ht = ftanh(acch[reg] + Ph[reg]);
        float hn = hd[reg] + zz[reg] * (ht - hd[reg]);   // (1-z)h + z*h~
        hd[reg] = Gn[reg] * hn;                          // fold next-step decay
        hdec[(q * 4 + reg) * HP + col] = f2bf_fast(hd[reg]);
      }
    } else {
      #pragma unroll
      for (int reg = 0; reg < 4; ++reg) {
        float ht = ftanh(acch[reg] + Ph[reg]);
        float hn = hd[reg] + zz[reg] * (ht - hd[reg]);
        hfin[(q * 4 + reg) * HP + col] = hn;
      }
    }
    BAR_LDS();                                         // barrier 2

    cz = nz; cr = nr; chh = nh; cg = ng;
  }

  // fused classifier: 32 threads per batch row
  {
    int row = tid >> 5, j = tid & 31;
    float acc = 0.f;
    #pragma unroll
    for (int c0 = 0; c0 < 4; ++c0)
      acc += hfin[row * HP + j + c0 * 32] * Wout[j + c0 * 32];
    acc += statics[(size_t)(b0 + row) * S_ + j] * Wout[H_ + j];
    #pragma unroll
    for (int off = 16; off >= 1; off >>= 1)
      acc += __shfl_down(acc, off, 32);
    if (j == 0) out[b0 + row] = acc + bout[0];
  }
}

// --------------------------------------------------------------------------
static void launch_all(void* const* d_in, float* out, char* ws, hipStream_t stream)
{
  const float* x      = (const float*)d_in[0];
  const float* statics= (const float*)d_in[1];
  const float* mask   = (const float*)d_in[2];
  const float* delta  = (const float*)d_in[3];
  const float* xlast  = (const float*)d_in[4];
  const float* xmean  = (const float*)d_in[5];
  const float* hs0    = (const float*)d_in[6];
  const float* wdgx   = (const float*)d_in[7];
  const float* bdgx   = (const float*)d_in[8];
  const float* Wdgh   = (const float*)d_in[9];
  const float* bdgh   = (const float*)d_in[10];
  const float* Wz     = (const float*)d_in[11];
  const float* Uz     = (const float*)d_in[12];
  const float* Vz     = (const float*)d_in[13];
  const float* bz     = (const float*)d_in[14];
  const float* Wr     = (const float*)d_in[15];
  const float* Ur     = (const float*)d_in[16];
  const float* Vr     = (const float*)d_in[17];
  const float* br     = (const float*)d_in[18];
  const float* Wh     = (const float*)d_in[19];
  const float* Uh     = (const float*)d_in[20];
  const float* Vh     = (const float*)d_in[21];
  const float* bh     = (const float*)d_in[22];
  const float* Wout   = (const float*)d_in[23];
  const float* bout   = (const float*)d_in[24];

  const size_t eBytes = (size_t)M_ * NE * 2;          // bf16 E, always
  const size_t wBytes = (size_t)NE * KA * 2;
  unsigned short* E = (unsigned short*)ws;
  unsigned short* Wcat = (unsigned short*)(ws + eBytes);
  float* bias = (float*)(ws + eBytes + wBytes);

  prep_weights<<<768, 256, 0, stream>>>(Wz, Vz, Wr, Vr, Wh, Vh, Wdgh,
                                        bz, br, bh, bdgh, Wcat, bias);
  gemm_fused<<<M_ / 128, 512, 0, stream>>>(x, mask, delta, xlast, xmean,
                                           wdgx, bdgx, Wcat, bias, E);
  grud_scan<<<B_ / 16, 512, 0, stream>>>(E, Uz, Ur, Uh, hs0, statics, Wout, bout, out);
}

extern "C" void kernel_launch(void* const* d_in, const int* in_sizes, int n_in,
                              void* d_out, int out_size, void* d_ws, size_t ws_size,
                              hipStream_t stream)
{
  char* ws = (char*)d_ws;
  float* out = (float*)d_out;
  const size_t needBF = (size_t)M_ * NE * 2 + (size_t)NE * KA * 2 + 8192;  // ~135 MB
  if (ws_size >= needBF) launch_all(d_in, out, ws, stream);
  // else: workspace too small — launch nothing (fails visibly)
}